// Round 5
// baseline (717.468 us; speedup 1.0000x reference)
//
#include <hip/hip_runtime.h>
#include <hip/hip_bf16.h>
#include <stdint.h>

#define E_N 150000
#define IN 512
#define MAXLEN 240

// pair-class perm: 32 classes (tau*8+etype), each base 128-aligned
#define PPERM 154112          // >= E + 32*127, multiple of 128
#define NTILE2 1204           // PPERM/128 row-tiles
#define GRID_GEMM (NTILE2 * 8)

typedef __attribute__((ext_vector_type(8))) short short8;
typedef __attribute__((ext_vector_type(4))) float f32x4;

// ---------- ws layout (bytes) ----------
#define OFF_RB   0UL            // bf16 [240][512]        245760
#define OFF_W2   245760UL       // bf16 [32][1024][512]   33554432
#define OFF_B2   33800192UL     // f32  [32][1024]        131072
#define OFF_RW   33931264UL     // f32  [32][240][1024]   31457280
#define OFF_CNT  65388544UL     // int  [128]             512
#define OFF_PERM 65389056UL     // int  [PPERM]           616448
// total ~66 MB

static __device__ __forceinline__ short f2bf(float f) {
  union { float f; uint32_t u; } v; v.f = f;
  uint32_t u = v.u;
  uint32_t r = (u + 0x7fffu + ((u >> 16) & 1u)) >> 16;
  return (short)r;
}

static __device__ __forceinline__ uint32_t pk2(float a, float b) {
  union { __hip_bfloat162 h; uint32_t u; } v;
  v.h = __float22bfloat162_rn(make_float2(a, b));
  return v.u;
}

// R table in bf16: Rbf[p][o] = bf16(sum_i emb[p][i]*linW[o][i] + linB[o])
__global__ __launch_bounds__(256) void k_rte(const float* __restrict__ emb,
    const float* __restrict__ linW, const float* __restrict__ linB,
    short* __restrict__ Rbf) {
  __shared__ float x[IN];
  int p = blockIdx.x;
  for (int i = threadIdx.x; i < IN; i += 256) x[i] = emb[p * IN + i];
  __syncthreads();
  for (int o = threadIdx.x; o < IN; o += 256) {
    const float* w = linW + (long)o * IN;
    float s = 0.f;
#pragma unroll 4
    for (int k = 0; k < IN; k += 4) {
      float4 wv = *(const float4*)(w + k);
      s += wv.x * x[k] + wv.y * x[k + 1] + wv.z * x[k + 2] + wv.w * x[k + 3];
    }
    Rbf[p * IN + o] = f2bf(s + linB[o]);
  }
}

// Pair weights: W2[p=t*8+g][o][i] bf16, B2[p][o] f32.
// o<512: head h=o>>6, o'=o&63: sum_j Watt[g][o'][j]*K_W[t][h*64+j][i]  (+Kb for B2)
// o>=512: same with Wmsg/V_W/Vb.
// grid 512 = 32 pairs x 16 (8 K-heads + 8 V-heads)
__global__ __launch_bounds__(256) void k_wpair(
    const float* __restrict__ WattW, const float* __restrict__ WmsgW,
    const float* __restrict__ KW, const float* __restrict__ VW,
    const float* __restrict__ Kb, const float* __restrict__ Vb,
    short* __restrict__ W2, float* __restrict__ B2) {
  __shared__ float Tl[64][65];
  int blk = blockIdx.x;
  int p = blk >> 4, s = blk & 15;
  int t = p >> 3, g = p & 7;
  bool kside = s < 8;
  int h = kside ? s : s - 8;
  const float* T = (kside ? WattW : WmsgW) + (size_t)g * 4096;
  const float* S = (kside ? KW : VW) + ((size_t)t * 512 + h * 64) * 512;
  const float* bsrc = (kside ? Kb : Vb) + t * 512 + h * 64;
  int tid = threadIdx.x;
  for (int i = tid; i < 4096; i += 256) Tl[i >> 6][i & 63] = T[i];
  __syncthreads();
  int op = tid & 63, iq = tid >> 6;
  size_t obase = ((size_t)p * 1024 + (kside ? 0 : 512) + h * 64 + op) * 512;
  for (int i8 = 0; i8 < 16; i8++) {
    int i0 = iq * 128 + i8 * 8;
    float a0 = 0, a1 = 0, a2 = 0, a3 = 0, a4 = 0, a5 = 0, a6 = 0, a7 = 0;
    const float* sp0 = S + i0;
#pragma unroll 8
    for (int j = 0; j < 64; j++) {
      float tv = Tl[op][j];
      const float* sp = sp0 + j * 512;
      float4 s0 = *(const float4*)sp;
      float4 s1 = *(const float4*)(sp + 4);
      a0 += tv * s0.x; a1 += tv * s0.y; a2 += tv * s0.z; a3 += tv * s0.w;
      a4 += tv * s1.x; a5 += tv * s1.y; a6 += tv * s1.z; a7 += tv * s1.w;
    }
    short8 o8;
    o8[0] = f2bf(a0); o8[1] = f2bf(a1); o8[2] = f2bf(a2); o8[3] = f2bf(a3);
    o8[4] = f2bf(a4); o8[5] = f2bf(a5); o8[6] = f2bf(a6); o8[7] = f2bf(a7);
    *(short8*)(W2 + obase + i0) = o8;
  }
  if (tid < 64) {
    float b = 0;
#pragma unroll 8
    for (int j = 0; j < 64; j++) b += Tl[tid][j] * bsrc[j];
    B2[p * 1024 + (kside ? 0 : 512) + h * 64 + tid] = b;
  }
}

// RW2'[p][d][o] = sum_i Rbf[d][i]*W2[p][o][i] + B2[p][o]   (f32)
// 128x128 MFMA tile, grid 512 = 32p x 2 rowtiles x 8 coltiles
__global__ __launch_bounds__(256, 4) void k_rw2(
    const short* __restrict__ Rbf, const short* __restrict__ W2,
    const float* __restrict__ B2, float* __restrict__ RW) {
  __shared__ short sA[4096];
  __shared__ short sB[4096];
  int tid = threadIdx.x;
  int bid = blockIdx.x;
  int p = bid >> 4, rt = (bid >> 3) & 1, ctile = bid & 7;
  int n0 = ctile * 128;
  int r0 = rt * 128;

  int lane = tid & 63, w = tid >> 6, wm = w >> 1, wn = w & 1;

  int rS = w * 32 + (lane >> 2);
  int cS = lane & 3;
  int ch0 = (cS - (rS >> 1)) & 3;
  int ch1 = (cS - ((rS + 16) >> 1)) & 3;
  const char* rbb = (const char*)Rbf;
  const char* srcA0 = rbb + (size_t)(r0 + rS) * 1024 + ch0 * 16;
  const char* srcA1 = rbb + (size_t)(r0 + rS + 16) * 1024 + ch1 * 16;
  const char* wcb = (const char*)(W2 + ((size_t)p * 1024 + n0) * 512);
  const char* srcB0 = wcb + (size_t)rS * 1024 + ch0 * 16;
  const char* srcB1 = wcb + (size_t)(rS + 16) * 1024 + ch1 * 16;
  char* dA0 = (char*)sA + w * 2048;
  char* dA1 = (char*)sA + w * 2048 + 1024;
  char* dB0 = (char*)sB + w * 2048;
  char* dB1 = (char*)sB + w * 2048 + 1024;

  int aRow = wm * 64 + (lane & 15);
  int aOff = aRow * 64 + ((((lane >> 4) + (aRow >> 1)) & 3) << 4);
  int bRow = wn * 64 + (lane & 15);
  int bOff = bRow * 64 + ((((lane >> 4) + (bRow >> 1)) & 3) << 4);

  f32x4 acc[4][4] = {};
#pragma unroll
  for (int kk = 0; kk < 16; kk++) {
    __syncthreads();
    __builtin_amdgcn_global_load_lds((const uint32_t*)(srcA0 + kk * 64), (uint32_t*)dA0, 16, 0, 0);
    __builtin_amdgcn_global_load_lds((const uint32_t*)(srcA1 + kk * 64), (uint32_t*)dA1, 16, 0, 0);
    __builtin_amdgcn_global_load_lds((const uint32_t*)(srcB0 + kk * 64), (uint32_t*)dB0, 16, 0, 0);
    __builtin_amdgcn_global_load_lds((const uint32_t*)(srcB1 + kk * 64), (uint32_t*)dB1, 16, 0, 0);
    __syncthreads();
    short8 a[4], b[4];
#pragma unroll
    for (int mi = 0; mi < 4; mi++)
      a[mi] = *(const short8*)((const char*)sA + aOff + mi * 1024);
#pragma unroll
    for (int ni = 0; ni < 4; ni++)
      b[ni] = *(const short8*)((const char*)sB + bOff + ni * 1024);
#pragma unroll
    for (int mi = 0; mi < 4; mi++)
#pragma unroll
      for (int ni = 0; ni < 4; ni++)
        acc[mi][ni] = __builtin_amdgcn_mfma_f32_16x16x32_bf16(a[mi], b[ni], acc[mi][ni], 0, 0, 0);
  }

  int l15 = lane & 15;
  int rbase = (lane >> 4) * 4;
  float bias[4];
#pragma unroll
  for (int ni = 0; ni < 4; ni++)
    bias[ni] = B2[p * 1024 + n0 + wn * 64 + ni * 16 + l15];
#pragma unroll
  for (int mi = 0; mi < 4; mi++) {
#pragma unroll
    for (int r = 0; r < 4; r++) {
      int row = r0 + wm * 64 + mi * 16 + rbase + r;
      if (row >= MAXLEN) continue;
      float* dst = RW + ((size_t)p * 240 + row) * 1024 + n0 + wn * 64;
#pragma unroll
      for (int ni = 0; ni < 4; ni++)
        dst[ni * 16 + l15] = acc[mi][ni][r] + bias[ni];
    }
  }
}

__global__ __launch_bounds__(256) void k_hist(const int* __restrict__ tau,
    const int* __restrict__ et, int* __restrict__ cnt) {
  __shared__ int l[32];
  if (threadIdx.x < 32) l[threadIdx.x] = 0;
  __syncthreads();
  int e = blockIdx.x * 256 + threadIdx.x;
  if (e < E_N) atomicAdd(&l[tau[e] * 8 + et[e]], 1);
  __syncthreads();
  if (threadIdx.x < 32) atomicAdd(&cnt[threadIdx.x], l[threadIdx.x]);
}

// c: [0..31]=cnt [32..63]=base(128-aligned) [64..95]=cursor
__global__ void k_bases(int* c) {
  int b = 0;
  for (int p = 0; p < 32; p++) {
    c[32 + p] = b;
    b += ((c[p] + 127) >> 7) << 7;
    c[64 + p] = 0;
  }
}

__global__ __launch_bounds__(256) void k_scatter(const int* __restrict__ tau,
    const int* __restrict__ et, int* __restrict__ c, int* __restrict__ perm) {
  __shared__ int lc[32], lbase[32];
  if (threadIdx.x < 32) lc[threadIdx.x] = 0;
  __syncthreads();
  int e = blockIdx.x * 256 + threadIdx.x;
  bool v = e < E_N;
  int cls = 0, pos = 0;
  if (v) {
    cls = tau[e] * 8 + et[e];
    pos = atomicAdd(&lc[cls], 1);
  }
  __syncthreads();
  if (threadIdx.x < 32) {
    int n = lc[threadIdx.x];
    lbase[threadIdx.x] = (n > 0) ? atomicAdd(&c[64 + threadIdx.x], n) : 0;
  }
  __syncthreads();
  if (v) perm[c[32 + cls] + lbase[cls] + pos] = e;
}

// Fused GEMM: per 128-edge pair-uniform tile, C[128][1024] = h_s(bf16) @ W2[p]^T.
// Epilogue adds RW2'[p][dt[e]] (R-part + bias). ctile<4 -> att (Q-dot),
// ctile>=4 -> M f32 direct to d_out.
// sA: linear [128 rows][32 k] bf16 with chunk-swizzle slot=(c+(row>>1))&3 —
// same layout the proven 0-conflict gload_lds path produces; reg-staged
// writes land on swizzled slots (<=2-way on both write and read = free).
__global__ __launch_bounds__(256, 4) void k_gemm(
    const float* __restrict__ hs, const int* __restrict__ dt,
    const int* __restrict__ tau, const int* __restrict__ et,
    const short* __restrict__ W2, const float* __restrict__ RW,
    const float* __restrict__ Qt, const float* __restrict__ mu,
    const int* __restrict__ perm,
    float* __restrict__ Mout, float* __restrict__ attOut) {
  __shared__ short sA[4096];      // chunk-swizzled linear, reg-staged
  __shared__ short sB[4096];      // chunk-swizzled, global_load_lds
  __shared__ int eRow[128];
  __shared__ int dtRow[128];
  __shared__ int metaP;
  int tid = threadIdx.x;
  // XCD swizzle: 9632 = 8*1204; one panel's 8 ctiles land on one XCD
  int l = (blockIdx.x & 7) * NTILE2 + (blockIdx.x >> 3);
  int ttile = l >> 3, ctile = l & 7;
  int m0 = ttile * 128;
  if (tid < 128) {
    int e = perm[m0 + tid];
    eRow[tid] = e;
    dtRow[tid] = (e >= 0) ? dt[e] : 0;
  }
  if (tid == 0) {
    int e0 = perm[m0];
    metaP = (e0 >= 0) ? (tau[e0] * 8 + et[e0]) : -1;
  }
  __syncthreads();
  int p = metaP;
  if (p < 0) return;
  int n0 = ctile * 128;

  int lane = tid & 63, w = tid >> 6, wm = w >> 1, wn = w & 1;

  // A staging: thread -> row = tid>>1, source chunks c0=(tid&1)*2, c0+1
  int arow = tid >> 1;
  int ahalf = tid & 1;
  long aE = eRow[arow]; if (aE < 0) aE = 0;
  const float* asrc = hs + aE * 512 + ahalf * 16;
  int swzA = (arow >> 1) & 3;
  int c0 = ahalf * 2;
  char* wA0 = (char*)sA + arow * 64 + (((c0    ) + swzA) & 3) * 16;
  char* wA1 = (char*)sA + arow * 64 + (((c0 + 1) + swzA) & 3) * 16;

  // B staging (proven round-3 path)
  int rS = w * 32 + (lane >> 2);
  int cS = lane & 3;
  int ch0 = (cS - (rS >> 1)) & 3;
  int ch1 = (cS - ((rS + 16) >> 1)) & 3;
  const char* wcb = (const char*)(W2 + ((size_t)p * 1024 + n0) * 512);
  const char* srcB0 = wcb + (size_t)rS * 1024 + ch0 * 16;
  const char* srcB1 = wcb + (size_t)(rS + 16) * 1024 + ch1 * 16;
  char* dB0 = (char*)sB + w * 2048;
  char* dB1 = (char*)sB + w * 2048 + 1024;

  int aRowF = wm * 64 + (lane & 15);
  int aOff = aRowF * 64 + ((((lane >> 4) + (aRowF >> 1)) & 3) << 4);
  int bRow = wn * 64 + (lane & 15);
  int bOff = bRow * 64 + ((((lane >> 4) + (bRow >> 1)) & 3) << 4);

  f32x4 acc[4][4] = {};
  float4 pf0 = *(const float4*)(asrc);
  float4 pf1 = *(const float4*)(asrc + 4);
  float4 pf2 = *(const float4*)(asrc + 8);
  float4 pf3 = *(const float4*)(asrc + 12);
#pragma unroll
  for (int kk = 0; kk < 16; kk++) {
    __syncthreads();
    union { short8 s; uint32_t u[4]; } w0, w1;
    w0.u[0] = pk2(pf0.x, pf0.y); w0.u[1] = pk2(pf0.z, pf0.w);
    w0.u[2] = pk2(pf1.x, pf1.y); w0.u[3] = pk2(pf1.z, pf1.w);
    w1.u[0] = pk2(pf2.x, pf2.y); w1.u[1] = pk2(pf2.z, pf2.w);
    w1.u[2] = pk2(pf3.x, pf3.y); w1.u[3] = pk2(pf3.z, pf3.w);
    *(short8*)wA0 = w0.s;
    *(short8*)wA1 = w1.s;
    __builtin_amdgcn_global_load_lds((const uint32_t*)(srcB0 + kk * 64), (uint32_t*)dB0, 16, 0, 0);
    __builtin_amdgcn_global_load_lds((const uint32_t*)(srcB1 + kk * 64), (uint32_t*)dB1, 16, 0, 0);
    if (kk < 15) {
      const float* np = asrc + (kk + 1) * 32;
      pf0 = *(const float4*)(np);
      pf1 = *(const float4*)(np + 4);
      pf2 = *(const float4*)(np + 8);
      pf3 = *(const float4*)(np + 12);
    }
    __syncthreads();
    short8 a[4], b[4];
#pragma unroll
    for (int mi = 0; mi < 4; mi++)
      a[mi] = *(const short8*)((const char*)sA + aOff + mi * 1024);
#pragma unroll
    for (int ni = 0; ni < 4; ni++)
      b[ni] = *(const short8*)((const char*)sB + bOff + ni * 1024);
#pragma unroll
    for (int mi = 0; mi < 4; mi++)
#pragma unroll
      for (int ni = 0; ni < 4; ni++)
        acc[mi][ni] = __builtin_amdgcn_mfma_f32_16x16x32_bf16(a[mi], b[ni], acc[mi][ni], 0, 0, 0);
  }

  // epilogue
  int l15 = lane & 15;
  int rbase = (lane >> 4) * 4;
  if (ctile < 4) {
    int h = ctile * 2 + wn;
    float muv = mu[(p & 7) * 8 + h] * 0.125f;
#pragma unroll
    for (int mi = 0; mi < 4; mi++) {
#pragma unroll
      for (int r = 0; r < 4; r++) {
        int row = wm * 64 + mi * 16 + rbase + r;
        int e = eRow[row];
        if (e < 0) continue;
        const float* rw = RW + ((size_t)p * 240 + dtRow[row]) * 1024 + n0 + wn * 64;
        const float* qp = Qt + (size_t)e * 512 + h * 64;
        float s = 0.f;
#pragma unroll
        for (int ni = 0; ni < 4; ni++)
          s += qp[ni * 16 + l15] * (acc[mi][ni][r] + rw[ni * 16 + l15]);
        s += __shfl_xor(s, 1);
        s += __shfl_xor(s, 2);
        s += __shfl_xor(s, 4);
        s += __shfl_xor(s, 8);
        if (l15 == 0) attOut[(size_t)e * 8 + h] = s * muv;
      }
    }
  } else {
#pragma unroll
    for (int mi = 0; mi < 4; mi++) {
#pragma unroll
      for (int r = 0; r < 4; r++) {
        int row = wm * 64 + mi * 16 + rbase + r;
        int e = eRow[row];
        if (e < 0) continue;
        const float* rw = RW + ((size_t)p * 240 + dtRow[row]) * 1024 + n0 + wn * 64;
        float* md = Mout + (size_t)e * 512 + (n0 - 512) + wn * 64;
#pragma unroll
        for (int ni = 0; ni < 4; ni++)
          md[ni * 16 + l15] = acc[mi][ni][r] + rw[ni * 16 + l15];
      }
    }
  }
}

extern "C" void kernel_launch(void* const* d_in, const int* in_sizes, int n_in,
                              void* d_out, int out_size, void* d_ws, size_t ws_size,
                              hipStream_t stream) {
  const float* hs    = (const float*)d_in[0];
  const float* Qt    = (const float*)d_in[1];
  const int*   et    = (const int*)d_in[2];
  const int*   tau   = (const int*)d_in[3];
  const int*   dt    = (const int*)d_in[4];
  const float* emb   = (const float*)d_in[5];
  const float* linW  = (const float*)d_in[6];
  const float* linB  = (const float*)d_in[7];
  const float* KW    = (const float*)d_in[8];
  const float* Kb    = (const float*)d_in[9];
  const float* VW    = (const float*)d_in[10];
  const float* Vb    = (const float*)d_in[11];
  const float* WattW = (const float*)d_in[12];
  const float* WmsgW = (const float*)d_in[13];
  const float* mu    = (const float*)d_in[14];

  char* ws = (char*)d_ws;
  short* Rbf  = (short*)(ws + OFF_RB);
  short* W2   = (short*)(ws + OFF_W2);
  float* B2   = (float*)(ws + OFF_B2);
  float* RW   = (float*)(ws + OFF_RW);
  int*   cnt  = (int*)(ws + OFF_CNT);
  int*   perm = (int*)(ws + OFF_PERM);

  float* attOut = (float*)d_out;
  float* Mout   = (float*)d_out + (long)E_N * 8;

  hipMemsetAsync(cnt, 0, 128 * sizeof(int), stream);
  hipMemsetAsync(perm, 0xFF, PPERM * sizeof(int), stream);

  k_rte<<<240, 256, 0, stream>>>(emb, linW, linB, Rbf);
  k_wpair<<<512, 256, 0, stream>>>(WattW, WmsgW, KW, VW, Kb, Vb, W2, B2);
  k_hist<<<(E_N + 255) / 256, 256, 0, stream>>>(tau, et, cnt);
  k_bases<<<1, 1, 0, stream>>>(cnt);
  k_scatter<<<(E_N + 255) / 256, 256, 0, stream>>>(tau, et, cnt, perm);
  k_rw2<<<512, 256, 0, stream>>>(Rbf, W2, B2, RW);
  k_gemm<<<GRID_GEMM, 256, 0, stream>>>(hs, dt, tau, et, W2, RW, Qt, mu, perm, Mout, attOut);
}

// Round 6
// 696.436 us; speedup vs baseline: 1.0302x; 1.0302x over previous
//
#include <hip/hip_runtime.h>
#include <hip/hip_bf16.h>
#include <stdint.h>

#define E_N 150000
#define IN 512
#define MAXLEN 240

// pair-class perm: 32 classes (tau*8+etype), each base 128-aligned
#define PPERM 154112          // >= E + 32*127, multiple of 128
#define NTILE2 1204           // PPERM/128 row-tiles
#define GRID_GEMM (NTILE2 * 8)

typedef __attribute__((ext_vector_type(8))) short short8;
typedef __attribute__((ext_vector_type(4))) float f32x4;

// ---------- ws layout (bytes) ----------
#define OFF_RB   0UL            // bf16 [240][512]        245760
#define OFF_W2   245760UL       // bf16 [32][1024][512]   33554432
#define OFF_B2   33800192UL     // f32  [32][1024]        131072
#define OFF_RW   33931264UL     // f32  [32][240][1024]   31457280
#define OFF_CNT  65388544UL     // int  [128]             512
#define OFF_PERM 65389056UL     // int  [PPERM]           616448
// total ~66 MB

static __device__ __forceinline__ short f2bf(float f) {
  union { float f; uint32_t u; } v; v.f = f;
  uint32_t u = v.u;
  uint32_t r = (u + 0x7fffu + ((u >> 16) & 1u)) >> 16;
  return (short)r;
}

static __device__ __forceinline__ uint32_t pk2(float a, float b) {
  union { __hip_bfloat162 h; uint32_t u; } v;
  v.h = __float22bfloat162_rn(make_float2(a, b));
  return v.u;
}

// R table in bf16: Rbf[p][o] = bf16(sum_i emb[p][i]*linW[o][i] + linB[o])
__global__ __launch_bounds__(256) void k_rte(const float* __restrict__ emb,
    const float* __restrict__ linW, const float* __restrict__ linB,
    short* __restrict__ Rbf) {
  __shared__ float x[IN];
  int p = blockIdx.x;
  for (int i = threadIdx.x; i < IN; i += 256) x[i] = emb[p * IN + i];
  __syncthreads();
  for (int o = threadIdx.x; o < IN; o += 256) {
    const float* w = linW + (long)o * IN;
    float s = 0.f;
#pragma unroll 4
    for (int k = 0; k < IN; k += 4) {
      float4 wv = *(const float4*)(w + k);
      s += wv.x * x[k] + wv.y * x[k + 1] + wv.z * x[k + 2] + wv.w * x[k + 3];
    }
    Rbf[p * IN + o] = f2bf(s + linB[o]);
  }
}

// Pair weights: W2[p=t*8+g][o][i] bf16, B2[p][o] f32.
// grid 2048 = 32 pairs x 16 (8 K-heads + 8 V-heads) x 4 i-quarters
__global__ __launch_bounds__(256) void k_wpair(
    const float* __restrict__ WattW, const float* __restrict__ WmsgW,
    const float* __restrict__ KW, const float* __restrict__ VW,
    const float* __restrict__ Kb, const float* __restrict__ Vb,
    short* __restrict__ W2, float* __restrict__ B2) {
  __shared__ float Tl[64][65];
  int blk = blockIdx.x;
  int p = blk >> 6, s = (blk >> 2) & 15, q = blk & 3;
  int t = p >> 3, g = p & 7;
  bool kside = s < 8;
  int h = kside ? s : s - 8;
  const float* T = (kside ? WattW : WmsgW) + (size_t)g * 4096;
  const float* S = (kside ? KW : VW) + ((size_t)t * 512 + h * 64) * 512;
  const float* bsrc = (kside ? Kb : Vb) + t * 512 + h * 64;
  int tid = threadIdx.x;
  for (int i = tid; i < 4096; i += 256) Tl[i >> 6][i & 63] = T[i];
  __syncthreads();
  int op = tid & 63, iq = tid >> 6;
  size_t obase = ((size_t)p * 1024 + (kside ? 0 : 512) + h * 64 + op) * 512;
  for (int i8 = q * 4; i8 < q * 4 + 4; i8++) {
    int i0 = iq * 128 + i8 * 8;
    float a0 = 0, a1 = 0, a2 = 0, a3 = 0, a4 = 0, a5 = 0, a6 = 0, a7 = 0;
    const float* sp0 = S + i0;
#pragma unroll 8
    for (int j = 0; j < 64; j++) {
      float tv = Tl[op][j];
      const float* sp = sp0 + j * 512;
      float4 s0 = *(const float4*)sp;
      float4 s1 = *(const float4*)(sp + 4);
      a0 += tv * s0.x; a1 += tv * s0.y; a2 += tv * s0.z; a3 += tv * s0.w;
      a4 += tv * s1.x; a5 += tv * s1.y; a6 += tv * s1.z; a7 += tv * s1.w;
    }
    short8 o8;
    o8[0] = f2bf(a0); o8[1] = f2bf(a1); o8[2] = f2bf(a2); o8[3] = f2bf(a3);
    o8[4] = f2bf(a4); o8[5] = f2bf(a5); o8[6] = f2bf(a6); o8[7] = f2bf(a7);
    *(short8*)(W2 + obase + i0) = o8;
  }
  if (q == 0 && tid < 64) {
    float b = 0;
#pragma unroll 8
    for (int j = 0; j < 64; j++) b += Tl[tid][j] * bsrc[j];
    B2[p * 1024 + (kside ? 0 : 512) + h * 64 + tid] = b;
  }
}

// RW2'[p][d][o] = sum_i Rbf[d][i]*W2[p][o][i] + B2[p][o]   (f32)
__global__ __launch_bounds__(256, 4) void k_rw2(
    const short* __restrict__ Rbf, const short* __restrict__ W2,
    const float* __restrict__ B2, float* __restrict__ RW) {
  __shared__ short sA[4096];
  __shared__ short sB[4096];
  int tid = threadIdx.x;
  int bid = blockIdx.x;
  int p = bid >> 4, rt = (bid >> 3) & 1, ctile = bid & 7;
  int n0 = ctile * 128;
  int r0 = rt * 128;

  int lane = tid & 63, w = tid >> 6, wm = w >> 1, wn = w & 1;

  int rS = w * 32 + (lane >> 2);
  int cS = lane & 3;
  int ch0 = (cS - (rS >> 1)) & 3;
  int ch1 = (cS - ((rS + 16) >> 1)) & 3;
  const char* rbb = (const char*)Rbf;
  const char* srcA0 = rbb + (size_t)(r0 + rS) * 1024 + ch0 * 16;
  const char* srcA1 = rbb + (size_t)(r0 + rS + 16) * 1024 + ch1 * 16;
  const char* wcb = (const char*)(W2 + ((size_t)p * 1024 + n0) * 512);
  const char* srcB0 = wcb + (size_t)rS * 1024 + ch0 * 16;
  const char* srcB1 = wcb + (size_t)(rS + 16) * 1024 + ch1 * 16;
  char* dA0 = (char*)sA + w * 2048;
  char* dA1 = (char*)sA + w * 2048 + 1024;
  char* dB0 = (char*)sB + w * 2048;
  char* dB1 = (char*)sB + w * 2048 + 1024;

  int aRow = wm * 64 + (lane & 15);
  int aOff = aRow * 64 + ((((lane >> 4) + (aRow >> 1)) & 3) << 4);
  int bRow = wn * 64 + (lane & 15);
  int bOff = bRow * 64 + ((((lane >> 4) + (bRow >> 1)) & 3) << 4);

  f32x4 acc[4][4] = {};
#pragma unroll
  for (int kk = 0; kk < 16; kk++) {
    __syncthreads();
    __builtin_amdgcn_global_load_lds((const uint32_t*)(srcA0 + kk * 64), (uint32_t*)dA0, 16, 0, 0);
    __builtin_amdgcn_global_load_lds((const uint32_t*)(srcA1 + kk * 64), (uint32_t*)dA1, 16, 0, 0);
    __builtin_amdgcn_global_load_lds((const uint32_t*)(srcB0 + kk * 64), (uint32_t*)dB0, 16, 0, 0);
    __builtin_amdgcn_global_load_lds((const uint32_t*)(srcB1 + kk * 64), (uint32_t*)dB1, 16, 0, 0);
    __syncthreads();
    short8 a[4], b[4];
#pragma unroll
    for (int mi = 0; mi < 4; mi++)
      a[mi] = *(const short8*)((const char*)sA + aOff + mi * 1024);
#pragma unroll
    for (int ni = 0; ni < 4; ni++)
      b[ni] = *(const short8*)((const char*)sB + bOff + ni * 1024);
#pragma unroll
    for (int mi = 0; mi < 4; mi++)
#pragma unroll
      for (int ni = 0; ni < 4; ni++)
        acc[mi][ni] = __builtin_amdgcn_mfma_f32_16x16x32_bf16(a[mi], b[ni], acc[mi][ni], 0, 0, 0);
  }

  int l15 = lane & 15;
  int rbase = (lane >> 4) * 4;
  float bias[4];
#pragma unroll
  for (int ni = 0; ni < 4; ni++)
    bias[ni] = B2[p * 1024 + n0 + wn * 64 + ni * 16 + l15];
#pragma unroll
  for (int mi = 0; mi < 4; mi++) {
#pragma unroll
    for (int r = 0; r < 4; r++) {
      int row = r0 + wm * 64 + mi * 16 + rbase + r;
      if (row >= MAXLEN) continue;
      float* dst = RW + ((size_t)p * 240 + row) * 1024 + n0 + wn * 64;
#pragma unroll
      for (int ni = 0; ni < 4; ni++)
        dst[ni * 16 + l15] = acc[mi][ni][r] + bias[ni];
    }
  }
}

__global__ __launch_bounds__(256) void k_hist(const int* __restrict__ tau,
    const int* __restrict__ et, int* __restrict__ cnt) {
  __shared__ int l[32];
  if (threadIdx.x < 32) l[threadIdx.x] = 0;
  __syncthreads();
  int e = blockIdx.x * 256 + threadIdx.x;
  if (e < E_N) atomicAdd(&l[tau[e] * 8 + et[e]], 1);
  __syncthreads();
  if (threadIdx.x < 32) atomicAdd(&cnt[threadIdx.x], l[threadIdx.x]);
}

// c: [0..31]=cnt [32..63]=base(128-aligned) [64..95]=cursor
__global__ void k_bases(int* c) {
  int b = 0;
  for (int p = 0; p < 32; p++) {
    c[32 + p] = b;
    b += ((c[p] + 127) >> 7) << 7;
    c[64 + p] = 0;
  }
}

__global__ __launch_bounds__(256) void k_scatter(const int* __restrict__ tau,
    const int* __restrict__ et, int* __restrict__ c, int* __restrict__ perm) {
  __shared__ int lc[32], lbase[32];
  if (threadIdx.x < 32) lc[threadIdx.x] = 0;
  __syncthreads();
  int e = blockIdx.x * 256 + threadIdx.x;
  bool v = e < E_N;
  int cls = 0, pos = 0;
  if (v) {
    cls = tau[e] * 8 + et[e];
    pos = atomicAdd(&lc[cls], 1);
  }
  __syncthreads();
  if (threadIdx.x < 32) {
    int n = lc[threadIdx.x];
    lbase[threadIdx.x] = (n > 0) ? atomicAdd(&c[64 + threadIdx.x], n) : 0;
  }
  __syncthreads();
  if (v) perm[c[32 + cls] + lbase[cls] + pos] = e;
}

// Fused GEMM: per 128-edge pair-uniform tile, C[128][1024] = h_s(bf16) @ W2[p]^T.
// 2-phase double-buffered pipeline: stage(next) issued BEFORE compute(cur),
// one barrier per k-step -> loads covered by the MFMA phase.
__global__ __launch_bounds__(256, 3) void k_gemm(
    const float* __restrict__ hs, const int* __restrict__ dt,
    const int* __restrict__ tau, const int* __restrict__ et,
    const short* __restrict__ W2, const float* __restrict__ RW,
    const float* __restrict__ Qt, const float* __restrict__ mu,
    const int* __restrict__ perm,
    float* __restrict__ Mout, float* __restrict__ attOut) {
  __shared__ short sA[2][4096];   // chunk-swizzled linear, reg-staged
  __shared__ short sB[2][4096];   // chunk-swizzled, global_load_lds
  __shared__ int eRow[128];
  __shared__ int dtRow[128];
  __shared__ int metaP;
  int tid = threadIdx.x;
  // XCD swizzle: 9632 = 8*1204; one panel's 8 ctiles land on one XCD
  int l = (blockIdx.x & 7) * NTILE2 + (blockIdx.x >> 3);
  int ttile = l >> 3, ctile = l & 7;
  int m0 = ttile * 128;
  if (tid < 128) {
    int e = perm[m0 + tid];
    eRow[tid] = e;
    dtRow[tid] = (e >= 0) ? dt[e] : 0;
  }
  if (tid == 0) {
    int e0 = perm[m0];
    metaP = (e0 >= 0) ? (tau[e0] * 8 + et[e0]) : -1;
  }
  __syncthreads();
  int p = metaP;
  if (p < 0) return;
  int n0 = ctile * 128;

  int lane = tid & 63, w = tid >> 6, wm = w >> 1, wn = w & 1;

  // A staging: thread -> row = tid>>1, 16 source floats at half (tid&1)
  int arow = tid >> 1;
  int ahalf = tid & 1;
  long aE = eRow[arow]; if (aE < 0) aE = 0;
  const float* asrc = hs + aE * 512 + ahalf * 16;
  int swzA = (arow >> 1) & 3;
  int c0 = ahalf * 2;
  int aw0 = arow * 64 + (((c0    ) + swzA) & 3) * 16;  // byte offsets in buf
  int aw1 = arow * 64 + (((c0 + 1) + swzA) & 3) * 16;

  // B staging (proven gload_lds + inverse chunk swizzle)
  int rS = w * 32 + (lane >> 2);
  int cS = lane & 3;
  int ch0 = (cS - (rS >> 1)) & 3;
  int ch1 = (cS - ((rS + 16) >> 1)) & 3;
  const char* wcb = (const char*)(W2 + ((size_t)p * 1024 + n0) * 512);
  const char* srcB0 = wcb + (size_t)rS * 1024 + ch0 * 16;
  const char* srcB1 = wcb + (size_t)(rS + 16) * 1024 + ch1 * 16;

  int aRowF = wm * 64 + (lane & 15);
  int aOff = aRowF * 64 + ((((lane >> 4) + (aRowF >> 1)) & 3) << 4);
  int bRow = wn * 64 + (lane & 15);
  int bOff = bRow * 64 + ((((lane >> 4) + (bRow >> 1)) & 3) << 4);

  float4 pf0, pf1, pf2, pf3;
#define LOADPF(k) { const float* np = asrc + (k) * 32; \
    pf0 = *(const float4*)(np); pf1 = *(const float4*)(np + 4); \
    pf2 = *(const float4*)(np + 8); pf3 = *(const float4*)(np + 12); }
#define CVTWRITE(buf) { union { short8 s; uint32_t u[4]; } w0_, w1_; \
    w0_.u[0] = pk2(pf0.x, pf0.y); w0_.u[1] = pk2(pf0.z, pf0.w); \
    w0_.u[2] = pk2(pf1.x, pf1.y); w0_.u[3] = pk2(pf1.z, pf1.w); \
    w1_.u[0] = pk2(pf2.x, pf2.y); w1_.u[1] = pk2(pf2.z, pf2.w); \
    w1_.u[2] = pk2(pf3.x, pf3.y); w1_.u[3] = pk2(pf3.z, pf3.w); \
    *(short8*)((char*)sA[buf] + aw0) = w0_.s; \
    *(short8*)((char*)sA[buf] + aw1) = w1_.s; }
#define STAGEB(k, buf) { \
    __builtin_amdgcn_global_load_lds((const uint32_t*)(srcB0 + (k) * 64), \
        (uint32_t*)((char*)sB[buf] + w * 2048), 16, 0, 0); \
    __builtin_amdgcn_global_load_lds((const uint32_t*)(srcB1 + (k) * 64), \
        (uint32_t*)((char*)sB[buf] + w * 2048 + 1024), 16, 0, 0); }

  f32x4 acc[4][4] = {};
  // prologue: stage k=0 into buf0, prefetch A-regs for k=1
  LOADPF(0);
  STAGEB(0, 0);
  CVTWRITE(0);
  LOADPF(1);
  __syncthreads();   // drains B(0) + A-regs(1); A(0) ds_writes visible

#pragma unroll
  for (int kk = 0; kk < 16; kk++) {
    int cur = kk & 1, nxt = cur ^ 1;
    if (kk < 15) {
      STAGEB(kk + 1, nxt);     // issued early: covered by compute below
      CVTWRITE(nxt);           // A-regs(kk+1) ready since last barrier
      if (kk < 14) LOADPF(kk + 2);
    }
    short8 a[4], b[4];
#pragma unroll
    for (int mi = 0; mi < 4; mi++)
      a[mi] = *(const short8*)((const char*)sA[cur] + aOff + mi * 1024);
#pragma unroll
    for (int ni = 0; ni < 4; ni++)
      b[ni] = *(const short8*)((const char*)sB[cur] + bOff + ni * 1024);
#pragma unroll
    for (int mi = 0; mi < 4; mi++)
#pragma unroll
      for (int ni = 0; ni < 4; ni++)
        acc[mi][ni] = __builtin_amdgcn_mfma_f32_16x16x32_bf16(a[mi], b[ni], acc[mi][ni], 0, 0, 0);
    __syncthreads();
  }
#undef LOADPF
#undef CVTWRITE
#undef STAGEB

  // epilogue
  int l15 = lane & 15;
  int rbase = (lane >> 4) * 4;
  if (ctile < 4) {
    int h = ctile * 2 + wn;
    float muv = mu[(p & 7) * 8 + h] * 0.125f;
#pragma unroll
    for (int mi = 0; mi < 4; mi++) {
#pragma unroll
      for (int r = 0; r < 4; r++) {
        int row = wm * 64 + mi * 16 + rbase + r;
        int e = eRow[row];
        if (e < 0) continue;
        const float* rw = RW + ((size_t)p * 240 + dtRow[row]) * 1024 + n0 + wn * 64;
        const float* qp = Qt + (size_t)e * 512 + h * 64;
        float s = 0.f;
#pragma unroll
        for (int ni = 0; ni < 4; ni++)
          s += qp[ni * 16 + l15] * (acc[mi][ni][r] + rw[ni * 16 + l15]);
        s += __shfl_xor(s, 1);
        s += __shfl_xor(s, 2);
        s += __shfl_xor(s, 4);
        s += __shfl_xor(s, 8);
        if (l15 == 0) attOut[(size_t)e * 8 + h] = s * muv;
      }
    }
  } else {
#pragma unroll
    for (int mi = 0; mi < 4; mi++) {
#pragma unroll
      for (int r = 0; r < 4; r++) {
        int row = wm * 64 + mi * 16 + rbase + r;
        int e = eRow[row];
        if (e < 0) continue;
        const float* rw = RW + ((size_t)p * 240 + dtRow[row]) * 1024 + n0 + wn * 64;
        float* md = Mout + (size_t)e * 512 + (n0 - 512) + wn * 64;
#pragma unroll
        for (int ni = 0; ni < 4; ni++)
          md[ni * 16 + l15] = acc[mi][ni][r] + rw[ni * 16 + l15];
      }
    }
  }
}

extern "C" void kernel_launch(void* const* d_in, const int* in_sizes, int n_in,
                              void* d_out, int out_size, void* d_ws, size_t ws_size,
                              hipStream_t stream) {
  const float* hs    = (const float*)d_in[0];
  const float* Qt    = (const float*)d_in[1];
  const int*   et    = (const int*)d_in[2];
  const int*   tau   = (const int*)d_in[3];
  const int*   dt    = (const int*)d_in[4];
  const float* emb   = (const float*)d_in[5];
  const float* linW  = (const float*)d_in[6];
  const float* linB  = (const float*)d_in[7];
  const float* KW    = (const float*)d_in[8];
  const float* Kb    = (const float*)d_in[9];
  const float* VW    = (const float*)d_in[10];
  const float* Vb    = (const float*)d_in[11];
  const float* WattW = (const float*)d_in[12];
  const float* WmsgW = (const float*)d_in[13];
  const float* mu    = (const float*)d_in[14];

  char* ws = (char*)d_ws;
  short* Rbf  = (short*)(ws + OFF_RB);
  short* W2   = (short*)(ws + OFF_W2);
  float* B2   = (float*)(ws + OFF_B2);
  float* RW   = (float*)(ws + OFF_RW);
  int*   cnt  = (int*)(ws + OFF_CNT);
  int*   perm = (int*)(ws + OFF_PERM);

  float* attOut = (float*)d_out;
  float* Mout   = (float*)d_out + (long)E_N * 8;

  hipMemsetAsync(cnt, 0, 128 * sizeof(int), stream);
  hipMemsetAsync(perm, 0xFF, PPERM * sizeof(int), stream);

  k_rte<<<240, 256, 0, stream>>>(emb, linW, linB, Rbf);
  k_wpair<<<2048, 256, 0, stream>>>(WattW, WmsgW, KW, VW, Kb, Vb, W2, B2);
  k_hist<<<(E_N + 255) / 256, 256, 0, stream>>>(tau, et, cnt);
  k_bases<<<1, 1, 0, stream>>>(cnt);
  k_scatter<<<(E_N + 255) / 256, 256, 0, stream>>>(tau, et, cnt, perm);
  k_rw2<<<512, 256, 0, stream>>>(Rbf, W2, B2, RW);
  k_gemm<<<GRID_GEMM, 256, 0, stream>>>(hs, dt, tau, et, W2, RW, Qt, mu, perm, Mout, attOut);
}